// Round 3
// baseline (308.446 us; speedup 1.0000x reference)
//
#include <hip/hip_runtime.h>
#include <stdint.h>

#define SEQ 1024
#define NB  1024
#define HD  64
#define BH  (NB*HD)            // 65536 elements per timestep plane
#define ROWS_PER_BLK 8

typedef _Float16 f16x8 __attribute__((ext_vector_type(8)));
typedef float    f32x4 __attribute__((ext_vector_type(4)));

// byte offset of 16B slot s within a 1KB region, XOR-swizzled for bank spread
__device__ __forceinline__ int swzb(int s) {
    return (s * 16) ^ (((s >> 3) & 7) << 4);
}
__device__ __forceinline__ uint32_t pkrtz(float a, float b) {
    auto h = __builtin_amdgcn_cvt_pkrtz(a, b);   // v_cvt_pkrtz_f16_f32
    return __builtin_bit_cast(uint32_t, h);
}
__device__ __forceinline__ float fast_tanh(float a) {
    // tanh(a) = 1 - 2/(exp2(a*2*log2e)+1); exact at +-inf
    float e = __builtin_amdgcn_exp2f(a * 2.8853900817779268f);
    return 1.0f - 2.0f * __builtin_amdgcn_rcpf(e + 1.0f);
}
// Barrier that drains ONLY lgkmcnt (LDS), leaving global loads/stores in
// flight across the barrier (avoids __syncthreads()'s vmcnt(0) drain).
__device__ __forceinline__ void sync_lds() {
    asm volatile("s_waitcnt lgkmcnt(0)" ::: "memory");
    __builtin_amdgcn_s_barrier();
    asm volatile("" ::: "memory");   // block hoisting reads above the barrier
}

__global__ __launch_bounds__(256) void rnn_kernel(
    const float* __restrict__ x,  const float* __restrict__ h0,
    const float* __restrict__ Wx, const float* __restrict__ bx,
    const float* __restrict__ Wh, const float* __restrict__ bh,
    float* __restrict__ out)
{
    // h: double-buffered [2][T][256dw]; x: quad-buffered [4][T][256dw]
    __shared__ __align__(16) uint32_t hK[2][2][256];
    __shared__ __align__(16) uint32_t xK[4][2][256];

    const int tid  = threadIdx.x;
    const int w    = tid >> 6;        // wave: owns output channels [16w,16w+16)
    const int lane = tid & 63;
    const int g    = lane >> 4;       // 16-lane group
    const int n    = lane & 15;       // MFMA col = batch row in block (valid < 8)
    const int R0   = blockIdx.x * ROWS_PER_BLK;

    // producer mapping: 256 threads stage one step's x (2KB) as f16 frags
    const int pT = tid >> 7;
    const int pr = tid & 127;
    const int pg = pr >> 5;
    const int pn = (pr >> 2) & 7;
    const int pq = pr & 3;
    const int k0 = pT * 32 + pg * 8 + pq * 2;
    const int pdw = (swzb(pg * 16 + pn) >> 2) + pq;
    const float* xprod = x + (size_t)(R0 + pn) * HD + k0;

    const int rdw = swzb(lane) >> 2;  // fragment read position (16B chunk)

    // h-fragment scatter: C-layout -> next-step B-frag slot
    const int hTw = w >> 1;
    const int hdw = (swzb((2 * (w & 1) + (g >> 1)) * 16 + n) >> 2) + 2 * (g & 1);

    // weights resident in VGPRs
    const int jrow = 16 * w + n;
    f16x8 whA[2], wxA[2];
    {
        const float* wr = Wh + (size_t)jrow * HD;
        const float* xr = Wx + (size_t)jrow * HD;
        #pragma unroll
        for (int T = 0; T < 2; ++T) {
            f16x8 aw, ax;
            #pragma unroll
            for (int e = 0; e < 8; ++e) {
                aw[e] = (_Float16)wr[T * 32 + g * 8 + e];
                ax[e] = (_Float16)xr[T * 32 + g * 8 + e];
            }
            whA[T] = aw; wxA[T] = ax;
        }
    }
    f32x4 bias;
    {
        const int j4 = 16 * w + 4 * g;
        #pragma unroll
        for (int r = 0; r < 4; ++r) bias[r] = bh[j4 + r] + bx[j4 + r];
    }

    // zero LDS (garbage cols n>=8 read zeros; column-isolated in MFMA anyway)
    {
        int4 z = {0, 0, 0, 0};
        ((int4*)hK)[tid] = z;
        ((int4*)xK)[tid] = z;
        ((int4*)xK)[tid + 256] = z;
    }
    sync_lds();

    // stage h_init, x(0), x(1)
    {
        float2 hv = *(const float2*)(h0 + (size_t)(R0 + pn) * HD + k0);
        hK[0][pT][pdw] = pkrtz(hv.x, hv.y);
        float2 x0v = *(const float2*)(xprod);
        xK[0][pT][pdw] = pkrtz(x0v.x, x0v.y);
        float2 x1v = *(const float2*)(xprod + (size_t)BH);
        xK[1][pT][pdw] = pkrtz(x1v.x, x1v.y);
    }
    // register ring: x(2..5)
    float2 r0 = *(const float2*)(xprod + (size_t)2 * BH);
    float2 r1 = *(const float2*)(xprod + (size_t)3 * BH);
    float2 r2 = *(const float2*)(xprod + (size_t)4 * BH);
    float2 r3 = *(const float2*)(xprod + (size_t)5 * BH);
    sync_lds();

    f16x8 fh0 = __builtin_bit_cast(f16x8, *(const int4*)&hK[0][0][rdw]);
    f16x8 fh1 = __builtin_bit_cast(f16x8, *(const int4*)&hK[0][1][rdw]);
    const f32x4 zf = {0.f, 0.f, 0.f, 0.f};
    f32x4 xpA, xpB;
    {   // xp for step 0
        f16x8 fx0 = __builtin_bit_cast(f16x8, *(const int4*)&xK[0][0][rdw]);
        f16x8 fx1 = __builtin_bit_cast(f16x8, *(const int4*)&xK[0][1][rdw]);
        xpA = __builtin_amdgcn_mfma_f32_16x16x32_f16(wxA[0], fx0, bias, 0, 0, 0);
        xpB = __builtin_amdgcn_mfma_f32_16x16x32_f16(wxA[1], fx1, zf,   0, 0, 0);
    }
    float* outlast = out + (size_t)SEQ * BH;

    auto STEP = [&](int t, float2& rn) {
        // critical chain: two PARALLEL Wh MFMAs (xp precomputed last step)
        f32x4 accA = __builtin_amdgcn_mfma_f32_16x16x32_f16(whA[0], fh0, xpA, 0, 0, 0);
        f32x4 accB = __builtin_amdgcn_mfma_f32_16x16x32_f16(whA[1], fh1, xpB, 0, 0, 0);

        // off-chain: stage x(t+2) into quad buffer, refill ring with x(t+6)
        if (t + 2 < SEQ) xK[(t + 2) & 3][pT][pdw] = pkrtz(rn.x, rn.y);
        {
            int tl = t + 6; if (tl > SEQ - 1) tl = SEQ - 1;
            rn = *(const float2*)(xprod + (size_t)tl * BH);
        }
        // off-chain: next step's x-projection
        if (t + 1 < SEQ) {
            f16x8 fxn0 = __builtin_bit_cast(f16x8, *(const int4*)&xK[(t + 1) & 3][0][rdw]);
            f16x8 fxn1 = __builtin_bit_cast(f16x8, *(const int4*)&xK[(t + 1) & 3][1][rdw]);
            xpA = __builtin_amdgcn_mfma_f32_16x16x32_f16(wxA[0], fxn0, bias, 0, 0, 0);
            xpB = __builtin_amdgcn_mfma_f32_16x16x32_f16(wxA[1], fxn1, zf,   0, 0, 0);
        }

        f32x4 acc = accA + accB;
        float hv0 = fast_tanh(acc[0]);
        float hv1 = fast_tanh(acc[1]);
        float hv2 = fast_tanh(acc[2]);
        float hv3 = fast_tanh(acc[3]);

        if (t + 1 < SEQ) {
            *(int2*)&hK[(t + 1) & 1][hTw][hdw] =
                make_int2((int)pkrtz(hv0, hv1), (int)pkrtz(hv2, hv3));
        }
        // off-chain: global store (vmcnt never drained -> fire and forget)
        if (n < 8) {
            float4 v = make_float4(hv0, hv1, hv2, hv3);
            float* dst = out + (size_t)t * BH + (size_t)(R0 + n) * HD + 16 * w + 4 * g;
            *(float4*)dst = v;
            if (t == SEQ - 1) {
                *(float4*)(outlast + (size_t)(R0 + n) * HD + 16 * w + 4 * g) = v;
            }
        }
        if (t + 1 < SEQ) {
            sync_lds();
            fh0 = __builtin_bit_cast(f16x8, *(const int4*)&hK[(t + 1) & 1][0][rdw]);
            fh1 = __builtin_bit_cast(f16x8, *(const int4*)&hK[(t + 1) & 1][1][rdw]);
        }
    };

    for (int tb = 0; tb < SEQ; tb += 4) {
        STEP(tb + 0, r0);
        STEP(tb + 1, r1);
        STEP(tb + 2, r2);
        STEP(tb + 3, r3);
    }
}

extern "C" void kernel_launch(void* const* d_in, const int* in_sizes, int n_in,
                              void* d_out, int out_size, void* d_ws, size_t ws_size,
                              hipStream_t stream) {
    const float* x  = (const float*)d_in[0];
    const float* h  = (const float*)d_in[1];
    const float* Wx = (const float*)d_in[2];
    const float* bx = (const float*)d_in[3];
    const float* Wh = (const float*)d_in[4];
    const float* bh = (const float*)d_in[5];
    float* out = (float*)d_out;

    rnn_kernel<<<dim3(NB / ROWS_PER_BLK), dim3(256), 0, stream>>>(x, h, Wx, bx, Wh, bh, out);
}